// Round 10
// baseline (168.394 us; speedup 1.0000x reference)
//
#include <hip/hip_runtime.h>
#include <hip/hip_bf16.h>
#include <math.h>

#define HW 6400
#define NC 512
#define NH 80
#define NW 80
#define NCH 25      // column chunks (blocks in y) for GEMM passes
#define NSLOT 50    // per-row gmax partial slots = NCH * 2
#define NCYS 8      // column chunks for streaming pass2
#define JCH 256     // columns per GEMM block
#define TI 128      // row tile per GEMM block
#define BK 64       // K tile
#define NT16 400    // 16x16 tiles per dimension (6400/16)

typedef __attribute__((ext_vector_type(8))) short short8;
typedef __attribute__((ext_vector_type(4))) float v4f;

// ---- workspace layout (float offsets) ----
#define MU_OFF    0
#define SQX_OFF   512                       // per-pixel sumsq partials (raw)
#define SQY_OFF   (512 + HW)
#define ACC_OFF   (512 + 2*HW)              // accum, counter (zeroed with SQ region)
#define GMAXP_OFF (ACC_OFF + 64)            // HW*NSLOT
#define GDIAG_OFF (GMAXP_OFF + HW*NSLOT)    // HW (fp32 diagonal cos); fallback: invd
#define ZP_OFF    (GDIAG_OFF + HW)          // HW*NSLOT (fallback) / HW*NCYS (stream)
#define F32_FLOATS (ZP_OFF + HW*NSLOT)
#define XB_BYTE   ((size_t)(((F32_FLOATS*4) + 255) & ~255))
#define YB_BYTE   (XB_BYTE + (size_t)HW*NC*2)
#define G_BYTE    (YB_BYTE + (size_t)HW*NC*2)
#define G_BYTES   ((size_t)NT16 * NT16 * 256)   // fp8: 40,960,000

// async global->LDS, 16 B per lane, LDS dest = wave-uniform base + lane*16
typedef __attribute__((address_space(1))) unsigned int uint_g;
typedef __attribute__((address_space(3))) unsigned int uint_l;
__device__ __forceinline__ void gload16(const void* g, void* l) {
    __builtin_amdgcn_global_load_lds((const uint_g*)g, (uint_l*)l, 16, 0, 0);
}

__device__ __forceinline__ float rnorm_of(float sq) {
    return 1.0f / fmaxf(sqrtf(sq), 1e-12f);
}

__global__ void k_mu(const float* __restrict__ y, float* __restrict__ mu) {
    int c = blockIdx.x;
    const float4* yc4 = (const float4*)(y + (size_t)c * HW);
    float s = 0.f;
    for (int i = threadIdx.x; i < HW / 4; i += 256) {
        float4 v = yc4[i];
        s += (v.x + v.y) + (v.z + v.w);
    }
    __shared__ float red[256];
    red[threadIdx.x] = s;
    __syncthreads();
    for (int off = 128; off > 0; off >>= 1) {
        if (threadIdx.x < off) red[threadIdx.x] += red[threadIdx.x + off];
        __syncthreads();
    }
    if (threadIdx.x == 0) mu[c] = red[0] * (1.0f / HW);
}

// centered bf16 transpose + per-pixel sumsq partials via atomicAdd.
// float4 global loads; LDS tile stride 65 -> <=2-way banks (free).
__global__ void k_transpose(const float* __restrict__ x, const float* __restrict__ y,
                            const float* __restrict__ mu,
                            float* __restrict__ sqx, float* __restrict__ sqy,
                            unsigned short* __restrict__ xb, unsigned short* __restrict__ yb) {
    __shared__ float tile[64 * 65];
    const int t = threadIdx.x;
    const int i0 = blockIdx.x * 64;
    const int c0 = blockIdx.y * 64;
    const int z = blockIdx.z;
    const float* src = z ? y : x;
    float* sq = z ? sqy : sqx;
    unsigned short* dst = z ? yb : xb;

    #pragma unroll
    for (int it = 0; it < 4; ++it) {
        int cl = it * 16 + (t >> 4);
        int p0 = (t & 15) * 4;
        float4 v = *(const float4*)(src + (size_t)(c0 + cl) * HW + i0 + p0);
        float m = mu[c0 + cl];
        tile[(p0 + 0) * 65 + cl] = v.x - m;
        tile[(p0 + 1) * 65 + cl] = v.y - m;
        tile[(p0 + 2) * 65 + cl] = v.z - m;
        tile[(p0 + 3) * 65 + cl] = v.w - m;
    }
    __syncthreads();
    {
        int il = t & 63, q = t >> 6;
        float s = 0.f;
        #pragma unroll
        for (int cl = q * 16; cl < q * 16 + 16; ++cl) {
            float v = tile[il * 65 + cl];
            s = fmaf(v, v, s);
        }
        atomicAdd(&sq[i0 + il], s);
    }
    #pragma unroll
    for (int it = 0; it < 2; ++it) {
        int il = t >> 2;
        int seg = (t & 3) + it * 4;
        unsigned int pk[4];
        #pragma unroll
        for (int p = 0; p < 4; ++p) {
            float v0 = tile[il * 65 + seg * 8 + p * 2];
            float v1 = tile[il * 65 + seg * 8 + p * 2 + 1];
            __hip_bfloat16 h0 = __float2bfloat16(v0);
            __hip_bfloat16 h1 = __float2bfloat16(v1);
            unsigned short u0 = *reinterpret_cast<unsigned short*>(&h0);
            unsigned short u1 = *reinterpret_cast<unsigned short*>(&h1);
            pk[p] = (unsigned int)u0 | ((unsigned int)u1 << 16);
        }
        uint4 val = make_uint4(pk[0], pk[1], pk[2], pk[3]);
        *(uint4*)&dst[(size_t)(i0 + il) * NC + c0 + seg * 8] = val;
    }
}

__device__ __forceinline__ void rmax_epilogue(float (&rmax)[16], float* gmaxp,
                                              int i0, int wr, int wc, int lr, int lg) {
    #pragma unroll
    for (int u = 0; u < 16; ++u) {
        float v = rmax[u];
        v = fmaxf(v, __shfl_xor(v, 1));
        v = fmaxf(v, __shfl_xor(v, 2));
        v = fmaxf(v, __shfl_xor(v, 4));
        v = fmaxf(v, __shfl_xor(v, 8));
        if (lr == 0) {
            int row = i0 + wr * 64 + (u >> 2) * 16 + lg * 4 + (u & 3);
            gmaxp[(size_t)row * NSLOT + blockIdx.y * 2 + wc] = v;
        }
    }
}

// pass1 (stream): R7 geometry (64x64 wave tile, 32 KB LDS, 2-jt loop) at
// launch_bounds(256,2) — (256,3) raised VALUBusy 21->32% and regressed (R9).
// Epilogue: fp32 normalize, row-max partials, fp8-e4m3 packed G store; fp32
// diagonal store guarded by a wave-uniform diag-block test (~4% of blocks).
__global__ __launch_bounds__(256, 2) void k_pass1s(const unsigned short* __restrict__ Xb,
                                                   const unsigned short* __restrict__ Yb,
                                                   const float* __restrict__ sqx,
                                                   const float* __restrict__ sqy,
                                                   float* __restrict__ gmaxp,
                                                   float* __restrict__ gdiag,
                                                   unsigned int* __restrict__ G1) {
    __shared__ char sA[TI * BK * 2];   // 16 KB: [row][k] bf16, seg^(row&7) swizzle
    __shared__ char sB[TI * BK * 2];
    const int t = threadIdx.x;
    const int w = t >> 6, l = t & 63;
    const int wr = w >> 1, wc = w & 1;
    const int lr = l & 15, lg = l >> 4;
    const int i0 = blockIdx.x * TI;
    const int jbase = blockIdx.y * JCH;

    int aoff[4][2], boff[4][2];
    #pragma unroll
    for (int mt = 0; mt < 4; ++mt) {
        int row = wr * 64 + mt * 16 + lr;
        #pragma unroll
        for (int ks = 0; ks < 2; ++ks) {
            int seg = ks * 4 + lg;
            aoff[mt][ks] = row * 128 + ((seg ^ (row & 7)) * 16);
        }
    }
    #pragma unroll
    for (int nt = 0; nt < 4; ++nt) {
        int row = wc * 64 + nt * 16 + lr;
        #pragma unroll
        for (int ks = 0; ks < 2; ++ks) {
            int seg = ks * 4 + lg;
            boff[nt][ks] = row * 128 + ((seg ^ (row & 7)) * 16);
        }
    }
    const int strow = l >> 3;
    const int stcol = ((l & 7) ^ strow) * 8;
    char* dA0 = sA + (w * 4 + 0) * 1024;
    char* dA1 = sA + (w * 4 + 1) * 1024;
    char* dA2 = sA + (w * 4 + 2) * 1024;
    char* dA3 = sA + (w * 4 + 3) * 1024;
    char* dB0 = sB + (w * 4 + 0) * 1024;
    char* dB1 = sB + (w * 4 + 1) * 1024;
    char* dB2 = sB + (w * 4 + 2) * 1024;
    char* dB3 = sB + (w * 4 + 3) * 1024;
    const unsigned short* ga = Xb + (size_t)(i0 + w * 32 + strow) * NC + stcol;
    const unsigned short* gb0 = Yb + (size_t)(jbase + w * 32 + strow) * NC + stcol;

    float rsx[16];
    #pragma unroll
    for (int u = 0; u < 16; ++u) {
        int row = i0 + wr * 64 + (u >> 2) * 16 + lg * 4 + (u & 3);
        rsx[u] = rnorm_of(sqx[row]);
    }
    float rmax[16];
    #pragma unroll
    for (int u = 0; u < 16; ++u) rmax[u] = -3.0e38f;

    #pragma unroll 1
    for (int jt = 0; jt < JCH; jt += TI) {
        const unsigned short* gb = gb0 + (size_t)jt * NC;
        v4f acc[4][4];
        #pragma unroll
        for (int mt = 0; mt < 4; ++mt)
            #pragma unroll
            for (int nt = 0; nt < 4; ++nt)
                acc[mt][nt] = (v4f){0.f, 0.f, 0.f, 0.f};

        #pragma unroll 1
        for (int kt = 0; kt < NC; kt += BK) {
            __syncthreads();
            gload16(ga + kt,           dA0);
            gload16(ga + 8  * NC + kt, dA1);
            gload16(ga + 16 * NC + kt, dA2);
            gload16(ga + 24 * NC + kt, dA3);
            gload16(gb + kt,           dB0);
            gload16(gb + 8  * NC + kt, dB1);
            gload16(gb + 16 * NC + kt, dB2);
            gload16(gb + 24 * NC + kt, dB3);
            __syncthreads();
            #pragma unroll
            for (int ks = 0; ks < 2; ++ks) {
                short8 af[4], bf[4];
                #pragma unroll
                for (int mt = 0; mt < 4; ++mt) af[mt] = *(const short8*)&sA[aoff[mt][ks]];
                #pragma unroll
                for (int nt = 0; nt < 4; ++nt) bf[nt] = *(const short8*)&sB[boff[nt][ks]];
                #pragma unroll
                for (int mt = 0; mt < 4; ++mt)
                    #pragma unroll
                    for (int nt = 0; nt < 4; ++nt)
                        acc[mt][nt] = __builtin_amdgcn_mfma_f32_16x16x32_bf16(
                            af[mt], bf[nt], acc[mt][nt], 0, 0, 0);
            }
        }

        // epilogue for this jt tile
        const bool diagblk = (jbase + jt <= i0 + TI - 1) && (jbase + jt + TI - 1 >= i0);
        #pragma unroll
        for (int nt = 0; nt < 4; ++nt) {
            int col = jbase + jt + wc * 64 + nt * 16 + lr;
            float sy = rnorm_of(sqy[col]);
            int ct = col >> 4;
            #pragma unroll
            for (int mt = 0; mt < 4; ++mt) {
                float g0 = acc[mt][nt][0] * rsx[mt * 4 + 0] * sy;
                float g1 = acc[mt][nt][1] * rsx[mt * 4 + 1] * sy;
                float g2 = acc[mt][nt][2] * rsx[mt * 4 + 2] * sy;
                float g3 = acc[mt][nt][3] * rsx[mt * 4 + 3] * sy;
                rmax[mt * 4 + 0] = fmaxf(rmax[mt * 4 + 0], g0);
                rmax[mt * 4 + 1] = fmaxf(rmax[mt * 4 + 1], g1);
                rmax[mt * 4 + 2] = fmaxf(rmax[mt * 4 + 2], g2);
                rmax[mt * 4 + 3] = fmaxf(rmax[mt * 4 + 3], g3);
                unsigned int pk = __builtin_amdgcn_cvt_pk_fp8_f32(g0, g1, 0, false);
                pk = __builtin_amdgcn_cvt_pk_fp8_f32(g2, g3, pk, true);
                size_t rbase = (size_t)(i0 / 16 + wr * 4 + mt) * (NT16 * 64);
                G1[rbase + (size_t)ct * 64 + l] = pk;
                if (diagblk) {
                    int rowb = i0 + wr * 64 + mt * 16 + lg * 4;
                    if (col == rowb + 0) gdiag[col] = g0;
                    if (col == rowb + 1) gdiag[col] = g1;
                    if (col == rowb + 2) gdiag[col] = g2;
                    if (col == rowb + 3) gdiag[col] = g3;
                }
            }
        }
    }
    rmax_epilogue(rmax, gmaxp, i0, wr, wc, lr, lg);
}

// streaming pass2: read fp8 G tiles, inline dmin, exp-sum Z.
__global__ __launch_bounds__(256) void k_pass2s(const unsigned int* __restrict__ G1,
                                                const float* __restrict__ gmaxp,
                                                float* __restrict__ zp) {
    const int t = threadIdx.x;
    const int w = t >> 6, l = t & 63;
    const int lr = l & 15, lg = l >> 4;
    const int rt = blockIdx.x * 4 + w;
    const int cy = blockIdx.y;

    float m = -3.0e38f;
    {
        int row = rt * 16 + lr;
        #pragma unroll
        for (int k = 0; k < 13; ++k) {
            int s = lg + 4 * k;
            if (s < NSLOT) m = fmaxf(m, gmaxp[(size_t)row * NSLOT + s]);
        }
        m = fmaxf(m, __shfl_xor(m, 16));
        m = fmaxf(m, __shfl_xor(m, 32));
    }
    float inv_lr = 1.0f / ((1.0f - m) + 1e-5f);
    float c1[4], c2[4];
    #pragma unroll
    for (int r = 0; r < 4; ++r) {
        float iv = __shfl(inv_lr, lg * 4 + r);
        c2[r] = 2.0f * iv;
        c1[r] = 2.0f - 2.0f * iv;
    }

    const unsigned int* base = G1 + (size_t)rt * (NT16 * 64) + l;
    float zs[4] = {0.f, 0.f, 0.f, 0.f};
    #pragma unroll 4
    for (int ct = cy * 50; ct < cy * 50 + 50; ++ct) {
        unsigned int v = base[(size_t)ct * 64];
        float g0 = __builtin_amdgcn_cvt_f32_fp8(v, 0);
        float g1 = __builtin_amdgcn_cvt_f32_fp8(v, 1);
        float g2 = __builtin_amdgcn_cvt_f32_fp8(v, 2);
        float g3 = __builtin_amdgcn_cvt_f32_fp8(v, 3);
        zs[0] += __expf(fmaf(c2[0], g0, c1[0]));
        zs[1] += __expf(fmaf(c2[1], g1, c1[1]));
        zs[2] += __expf(fmaf(c2[2], g2, c1[2]));
        zs[3] += __expf(fmaf(c2[3], g3, c1[3]));
    }
    #pragma unroll
    for (int r = 0; r < 4; ++r) {
        float z = zs[r];
        z += __shfl_xor(z, 1);
        z += __shfl_xor(z, 2);
        z += __shfl_xor(z, 4);
        z += __shfl_xor(z, 8);
        if (lr == 0) {
            int row = rt * 16 + lg * 4 + r;
            zp[(size_t)row * NCYS + cy] = z;
        }
    }
}

__global__ void k_kmax_s(const float* __restrict__ zp, const float* __restrict__ gdiag,
                         const float* __restrict__ gmaxp, float* __restrict__ accum,
                         int* __restrict__ counter, float* __restrict__ out) {
    int i = blockIdx.x * 256 + threadIdx.x;
    float Z = 0.f, gmax = -3.0e38f;
    #pragma unroll
    for (int s = 0; s < NCYS; ++s) Z += zp[(size_t)i * NCYS + s];
    #pragma unroll
    for (int s = 0; s < NSLOT; ++s) gmax = fmaxf(gmax, gmaxp[(size_t)i * NSLOT + s]);
    float dmin = 1.0f - gmax;
    float inv = 1.0f / (dmin + 1e-5f);
    float wmx = __expf(2.0f - 2.0f * dmin * inv);
    float wii = __expf(2.0f - 2.0f * (1.0f - gdiag[i]) * inv);
    float invZ = 1.0f / Z;
    float kmax = fmaxf(0.9f * wmx * invZ, 0.9f * wii * invZ + 0.1f);

    __shared__ float red[256];
    red[threadIdx.x] = kmax;
    __syncthreads();
    for (int off = 128; off > 0; off >>= 1) {
        if (threadIdx.x < off) red[threadIdx.x] += red[threadIdx.x + off];
        __syncthreads();
    }
    if (threadIdx.x == 0) {
        atomicAdd(accum, red[0]);
        __threadfence();
        int n = atomicAdd(counter, 1);
        if (n == (int)gridDim.x - 1) {
            float total = atomicAdd(accum, 0.0f);
            out[0] = -logf(total * (1.0f / HW) + 1e-5f);
        }
    }
}

// ---------- fallback path (ws too small for G): two-GEMM ----------
template <typename F>
__device__ __forceinline__ void gemm_driver(const unsigned short* __restrict__ Xb,
                                            const unsigned short* __restrict__ Yb,
                                            F&& consume) {
    __shared__ char sA[TI * BK * 2];
    __shared__ char sB[TI * BK * 2];
    const int t = threadIdx.x;
    const int w = t >> 6, l = t & 63;
    const int wr = w >> 1, wc = w & 1;
    const int lr = l & 15, lg = l >> 4;
    const int i0 = blockIdx.x * TI;
    const int jbase = blockIdx.y * JCH;

    int aoff[4][2], boff[4][2];
    #pragma unroll
    for (int mt = 0; mt < 4; ++mt) {
        int row = wr * 64 + mt * 16 + lr;
        #pragma unroll
        for (int ks = 0; ks < 2; ++ks) {
            int seg = ks * 4 + lg;
            aoff[mt][ks] = row * 128 + ((seg ^ (row & 7)) * 16);
        }
    }
    #pragma unroll
    for (int nt = 0; nt < 4; ++nt) {
        int row = wc * 64 + nt * 16 + lr;
        #pragma unroll
        for (int ks = 0; ks < 2; ++ks) {
            int seg = ks * 4 + lg;
            boff[nt][ks] = row * 128 + ((seg ^ (row & 7)) * 16);
        }
    }
    const int strow = l >> 3;
    const int stcol = ((l & 7) ^ strow) * 8;
    char* dA0 = sA + (w * 4 + 0) * 1024;
    char* dA1 = sA + (w * 4 + 1) * 1024;
    char* dA2 = sA + (w * 4 + 2) * 1024;
    char* dA3 = sA + (w * 4 + 3) * 1024;
    char* dB0 = sB + (w * 4 + 0) * 1024;
    char* dB1 = sB + (w * 4 + 1) * 1024;
    char* dB2 = sB + (w * 4 + 2) * 1024;
    char* dB3 = sB + (w * 4 + 3) * 1024;
    const unsigned short* ga = Xb + (size_t)(i0 + w * 32 + strow) * NC + stcol;
    const unsigned short* gb0 = Yb + (size_t)(jbase + w * 32 + strow) * NC + stcol;

    #pragma unroll 1
    for (int jt = 0; jt < JCH; jt += TI) {
        const unsigned short* gb = gb0 + (size_t)jt * NC;
        v4f acc[4][4];
        #pragma unroll
        for (int mt = 0; mt < 4; ++mt)
            #pragma unroll
            for (int nt = 0; nt < 4; ++nt)
                acc[mt][nt] = (v4f){0.f, 0.f, 0.f, 0.f};

        #pragma unroll 1
        for (int kt = 0; kt < NC; kt += BK) {
            __syncthreads();
            gload16(ga + kt,           dA0);
            gload16(ga + 8  * NC + kt, dA1);
            gload16(ga + 16 * NC + kt, dA2);
            gload16(ga + 24 * NC + kt, dA3);
            gload16(gb + kt,           dB0);
            gload16(gb + 8  * NC + kt, dB1);
            gload16(gb + 16 * NC + kt, dB2);
            gload16(gb + 24 * NC + kt, dB3);
            __syncthreads();
            #pragma unroll
            for (int ks = 0; ks < 2; ++ks) {
                short8 af[4], bf[4];
                #pragma unroll
                for (int mt = 0; mt < 4; ++mt) af[mt] = *(const short8*)&sA[aoff[mt][ks]];
                #pragma unroll
                for (int nt = 0; nt < 4; ++nt) bf[nt] = *(const short8*)&sB[boff[nt][ks]];
                #pragma unroll
                for (int mt = 0; mt < 4; ++mt)
                    #pragma unroll
                    for (int nt = 0; nt < 4; ++nt)
                        acc[mt][nt] = __builtin_amdgcn_mfma_f32_16x16x32_bf16(
                            af[mt], bf[nt], acc[mt][nt], 0, 0, 0);
            }
        }
        consume(acc, jt);
    }
}

__global__ __launch_bounds__(256, 2) void k_pass1(const unsigned short* __restrict__ Xb,
                                                  const unsigned short* __restrict__ Yb,
                                                  const float* __restrict__ sqx,
                                                  const float* __restrict__ sqy,
                                                  float* __restrict__ gmaxp) {
    const int t = threadIdx.x;
    const int w = t >> 6, l = t & 63;
    const int wr = w >> 1, wc = w & 1;
    const int lr = l & 15, lg = l >> 4;
    const int i0 = blockIdx.x * TI;
    const int jbase = blockIdx.y * JCH;
    float rsx[16], rmax[16];
    #pragma unroll
    for (int u = 0; u < 16; ++u) {
        int row = i0 + wr * 64 + (u >> 2) * 16 + lg * 4 + (u & 3);
        rsx[u] = rnorm_of(sqx[row]);
        rmax[u] = -3.0e38f;
    }
    gemm_driver(Xb, Yb, [&](v4f (&acc)[4][4], int jt) {
        #pragma unroll
        for (int nt = 0; nt < 4; ++nt) {
            float sy = rnorm_of(sqy[jbase + jt + (wc * 4 + nt) * 16 + lr]);
            #pragma unroll
            for (int mt = 0; mt < 4; ++mt)
                #pragma unroll
                for (int r = 0; r < 4; ++r)
                    rmax[mt * 4 + r] = fmaxf(rmax[mt * 4 + r],
                                             acc[mt][nt][r] * rsx[mt * 4 + r] * sy);
        }
    });
    rmax_epilogue(rmax, gmaxp, i0, wr, wc, lr, lg);
}

__global__ void k_invd(const float* __restrict__ gmaxp, float* __restrict__ invd) {
    int i = blockIdx.x * 256 + threadIdx.x;
    float m = -3.0e38f;
    #pragma unroll
    for (int s = 0; s < NSLOT; ++s) m = fmaxf(m, gmaxp[(size_t)i * NSLOT + s]);
    invd[i] = 1.0f / ((1.0f - m) + 1e-5f);
}

__global__ __launch_bounds__(256, 2) void k_pass2(const unsigned short* __restrict__ Xb,
                                                  const unsigned short* __restrict__ Yb,
                                                  const float* __restrict__ sqx,
                                                  const float* __restrict__ sqy,
                                                  const float* __restrict__ invd,
                                                  float* __restrict__ zp) {
    const int t = threadIdx.x;
    const int w = t >> 6, l = t & 63;
    const int wr = w >> 1, wc = w & 1;
    const int lr = l & 15, lg = l >> 4;
    const int i0 = blockIdx.x * TI;
    const int jbase = blockIdx.y * JCH;
    float zs[16], c1[16], c2[16], rsx[16];
    #pragma unroll
    for (int u = 0; u < 16; ++u) {
        int row = i0 + wr * 64 + (u >> 2) * 16 + lg * 4 + (u & 3);
        float inv = invd[row];
        c2[u] = 2.0f * inv;
        c1[u] = 2.0f - 2.0f * inv;
        rsx[u] = rnorm_of(sqx[row]);
        zs[u] = 0.f;
    }
    gemm_driver(Xb, Yb, [&](v4f (&acc)[4][4], int jt) {
        #pragma unroll
        for (int nt = 0; nt < 4; ++nt) {
            float sy = rnorm_of(sqy[jbase + jt + (wc * 4 + nt) * 16 + lr]);
            #pragma unroll
            for (int mt = 0; mt < 4; ++mt)
                #pragma unroll
                for (int r = 0; r < 4; ++r) {
                    int u = mt * 4 + r;
                    float g = acc[mt][nt][r] * rsx[u] * sy;
                    zs[u] += __expf(fmaf(c2[u], g, c1[u]));
                }
        }
    });
    #pragma unroll
    for (int u = 0; u < 16; ++u) {
        float z = zs[u];
        z += __shfl_xor(z, 1);
        z += __shfl_xor(z, 2);
        z += __shfl_xor(z, 4);
        z += __shfl_xor(z, 8);
        if (lr == 0) {
            int row = i0 + wr * 64 + (u >> 2) * 16 + lg * 4 + (u & 3);
            zp[(size_t)row * NSLOT + blockIdx.y * 2 + wc] = z;
        }
    }
}

__global__ void k_kmax(const float* __restrict__ zp, const float* __restrict__ gmaxp,
                       const unsigned short* __restrict__ Xb, const unsigned short* __restrict__ Yb,
                       const float* __restrict__ sqx, const float* __restrict__ sqy,
                       float* __restrict__ accum, int* __restrict__ counter,
                       float* __restrict__ out) {
    int i = blockIdx.x * 256 + threadIdx.x;
    float Z = 0.f, gmax = -3.0e38f;
    #pragma unroll
    for (int s = 0; s < NSLOT; ++s) {
        Z += zp[(size_t)i * NSLOT + s];
        gmax = fmaxf(gmax, gmaxp[(size_t)i * NSLOT + s]);
    }
    float gii = 0.f;
    const uint2* xr = (const uint2*)(Xb + (size_t)i * NC);
    const uint2* yr = (const uint2*)(Yb + (size_t)i * NC);
    for (int c4 = 0; c4 < NC / 4; ++c4) {
        uint2 xa = xr[c4], ya = yr[c4];
        float x0 = __uint_as_float((xa.x & 0xFFFFu) << 16), y0 = __uint_as_float((ya.x & 0xFFFFu) << 16);
        float x1 = __uint_as_float(xa.x & 0xFFFF0000u),     y1 = __uint_as_float(ya.x & 0xFFFF0000u);
        float x2 = __uint_as_float((xa.y & 0xFFFFu) << 16), y2 = __uint_as_float((ya.y & 0xFFFFu) << 16);
        float x3 = __uint_as_float(xa.y & 0xFFFF0000u),     y3 = __uint_as_float(ya.y & 0xFFFF0000u);
        gii = fmaf(x0, y0, gii); gii = fmaf(x1, y1, gii);
        gii = fmaf(x2, y2, gii); gii = fmaf(x3, y3, gii);
    }
    gii *= rnorm_of(sqx[i]) * rnorm_of(sqy[i]);
    float dmin = 1.0f - gmax;
    float inv = 1.0f / (dmin + 1e-5f);
    float wmx = __expf(2.0f - 2.0f * dmin * inv);
    float wii = __expf(2.0f - 2.0f * (1.0f - gii) * inv);
    float invZ = 1.0f / Z;
    float kmax = fmaxf(0.9f * wmx * invZ, 0.9f * wii * invZ + 0.1f);

    __shared__ float red[256];
    red[threadIdx.x] = kmax;
    __syncthreads();
    for (int off = 128; off > 0; off >>= 1) {
        if (threadIdx.x < off) red[threadIdx.x] += red[threadIdx.x + off];
        __syncthreads();
    }
    if (threadIdx.x == 0) {
        atomicAdd(accum, red[0]);
        __threadfence();
        int n = atomicAdd(counter, 1);
        if (n == (int)gridDim.x - 1) {
            float total = atomicAdd(accum, 0.0f);
            out[0] = -logf(total * (1.0f / HW) + 1e-5f);
        }
    }
}

extern "C" void kernel_launch(void* const* d_in, const int* in_sizes, int n_in,
                              void* d_out, int out_size, void* d_ws, size_t ws_size,
                              hipStream_t stream) {
    const float* x = (const float*)d_in[0];
    const float* y = (const float*)d_in[1];
    float* out = (float*)d_out;
    float* ws = (float*)d_ws;

    float* mu    = ws + MU_OFF;
    float* sqx   = ws + SQX_OFF;
    float* sqy   = ws + SQY_OFF;
    float* accum = ws + ACC_OFF;
    int*   counter = (int*)(accum + 1);
    float* gmaxp = ws + GMAXP_OFF;
    float* gdiag = ws + GDIAG_OFF;   // fallback: invd
    float* zp    = ws + ZP_OFF;
    unsigned short* Xb = (unsigned short*)((char*)d_ws + XB_BYTE);
    unsigned short* Yb = (unsigned short*)((char*)d_ws + YB_BYTE);
    unsigned int*   G1 = (unsigned int*)((char*)d_ws + G_BYTE);

    const bool bigws = ws_size >= (G_BYTE + G_BYTES);

    // zero sumsq accumulators + accum/counter in one shot
    hipMemsetAsync(sqx, 0, (2 * HW + 64) * sizeof(float), stream);

    hipLaunchKernelGGL(k_mu, dim3(NC), dim3(256), 0, stream, y, mu);
    hipLaunchKernelGGL(k_transpose, dim3(HW / 64, NC / 64, 2), dim3(256), 0, stream,
                       x, y, mu, sqx, sqy, Xb, Yb);

    dim3 grid(HW / TI, NCH);
    if (bigws) {
        hipLaunchKernelGGL(k_pass1s, grid, dim3(256), 0, stream, Xb, Yb, sqx, sqy,
                           gmaxp, gdiag, G1);
        hipLaunchKernelGGL(k_pass2s, dim3(NT16 / 4, NCYS), dim3(256), 0, stream, G1, gmaxp, zp);
        hipLaunchKernelGGL(k_kmax_s, dim3(HW / 256), dim3(256), 0, stream, zp, gdiag, gmaxp,
                           accum, counter, out);
    } else {
        hipLaunchKernelGGL(k_pass1, grid, dim3(256), 0, stream, Xb, Yb, sqx, sqy, gmaxp);
        hipLaunchKernelGGL(k_invd, dim3(HW / 256), dim3(256), 0, stream, gmaxp, gdiag);
        hipLaunchKernelGGL(k_pass2, grid, dim3(256), 0, stream, Xb, Yb, sqx, sqy, gdiag, zp);
        hipLaunchKernelGGL(k_kmax, dim3(HW / 256), dim3(256), 0, stream, zp, gmaxp, Xb, Yb,
                           sqx, sqy, accum, counter, out);
    }
}

// Round 11
// 156.224 us; speedup vs baseline: 1.0779x; 1.0779x over previous
//
#include <hip/hip_runtime.h>
#include <hip/hip_bf16.h>
#include <math.h>

#define HW 6400
#define NC 512
#define NH 80
#define NW 80
#define NCH 25      // column chunks (blocks in y) for GEMM passes
#define NSLOT 50    // per-row gmax partial slots = NCH * 2
#define NCYS 8      // column chunks for streaming pass2
#define JCH 256     // columns per GEMM block
#define TI 128      // row tile per GEMM block
#define BK 64       // K tile
#define NT16 400    // 16x16 tiles per dimension (6400/16)

typedef __attribute__((ext_vector_type(8))) short short8;
typedef __attribute__((ext_vector_type(4))) float v4f;

// ---- workspace layout (float offsets) ----
#define MU_OFF    0
#define ACC_OFF   512                       // accum, counter
#define GMAXP_OFF (ACC_OFF + 64)            // HW*NSLOT; aliased by psx/psy pre-pass1
#define GDIAG_OFF (GMAXP_OFF + HW*NSLOT)    // HW (fp32 diagonal cos); fallback: invd
#define ZP_OFF    (GDIAG_OFF + HW)          // HW*NSLOT (fallback) / HW*NCYS (stream)
#define F32_FLOATS (ZP_OFF + HW*NSLOT)
#define XB_BYTE   ((size_t)(((F32_FLOATS*4) + 255) & ~255))
#define YB_BYTE   (XB_BYTE + (size_t)HW*NC*2)
#define G_BYTE    (YB_BYTE + (size_t)HW*NC*2)
#define G_BYTES   ((size_t)NT16 * NT16 * 256)   // fp8: 40,960,000

// async global->LDS, 16 B per lane, LDS dest = wave-uniform base + lane*16
typedef __attribute__((address_space(1))) unsigned int uint_g;
typedef __attribute__((address_space(3))) unsigned int uint_l;
__device__ __forceinline__ void gload16(const void* g, void* l) {
    __builtin_amdgcn_global_load_lds((const uint_g*)g, (uint_l*)l, 16, 0, 0);
}

__global__ void k_mu(const float* __restrict__ y, float* __restrict__ mu) {
    int c = blockIdx.x;
    const float4* yc4 = (const float4*)(y + (size_t)c * HW);
    float s = 0.f;
    for (int i = threadIdx.x; i < HW / 4; i += 256) {
        float4 v = yc4[i];
        s += (v.x + v.y) + (v.z + v.w);
    }
    __shared__ float red[256];
    red[threadIdx.x] = s;
    __syncthreads();
    for (int off = 128; off > 0; off >>= 1) {
        if (threadIdx.x < off) red[threadIdx.x] += red[threadIdx.x + off];
        __syncthreads();
    }
    if (threadIdx.x == 0) mu[c] = red[0] * (1.0f / HW);
}

// partial sum-of-squares over a 64-channel chunk; grid (HW/256, NC/64)
__global__ void k_sumsq(const float* __restrict__ x, const float* __restrict__ y,
                        const float* __restrict__ mu,
                        float* __restrict__ psx, float* __restrict__ psy) {
    int i = blockIdx.x * 256 + threadIdx.x;
    int c0 = blockIdx.y * 64;
    float sx = 0.f, sy = 0.f;
    for (int c = c0; c < c0 + 64; ++c) {
        float m = mu[c];
        float dx = x[(size_t)c * HW + i] - m;
        float dy = y[(size_t)c * HW + i] - m;
        sx = fmaf(dx, dx, sx);
        sy = fmaf(dy, dy, sy);
    }
    psx[(size_t)blockIdx.y * HW + i] = sx;
    psy[(size_t)blockIdx.y * HW + i] = sy;
}

// NORMALIZED bf16 transpose: dst[i][c] = (src[c][i]-mu[c]) / ||row i||.
// float4 global loads; LDS tile stride 65 -> <=2-way banks (free).
__global__ void k_transpose(const float* __restrict__ x, const float* __restrict__ y,
                            const float* __restrict__ mu,
                            const float* __restrict__ psx, const float* __restrict__ psy,
                            unsigned short* __restrict__ xb, unsigned short* __restrict__ yb) {
    __shared__ float tile[64 * 65];
    __shared__ float ssinv[64];
    const int t = threadIdx.x;
    const int i0 = blockIdx.x * 64;
    const int c0 = blockIdx.y * 64;
    const int z = blockIdx.z;
    const float* src = z ? y : x;
    const float* ps  = z ? psy : psx;
    unsigned short* dst = z ? yb : xb;

    if (t < 64) {
        float s = 0.f;
        #pragma unroll
        for (int p = 0; p < 8; ++p) s += ps[(size_t)p * HW + i0 + t];
        ssinv[t] = 1.0f / fmaxf(sqrtf(s), 1e-12f);
    }
    __syncthreads();
    #pragma unroll
    for (int it = 0; it < 4; ++it) {
        int cl = it * 16 + (t >> 4);
        int p0 = (t & 15) * 4;
        float4 v = *(const float4*)(src + (size_t)(c0 + cl) * HW + i0 + p0);
        float m = mu[c0 + cl];
        tile[(p0 + 0) * 65 + cl] = (v.x - m) * ssinv[p0 + 0];
        tile[(p0 + 1) * 65 + cl] = (v.y - m) * ssinv[p0 + 1];
        tile[(p0 + 2) * 65 + cl] = (v.z - m) * ssinv[p0 + 2];
        tile[(p0 + 3) * 65 + cl] = (v.w - m) * ssinv[p0 + 3];
    }
    __syncthreads();
    #pragma unroll
    for (int it = 0; it < 2; ++it) {
        int il = t >> 2;
        int seg = (t & 3) + it * 4;
        unsigned int pk[4];
        #pragma unroll
        for (int p = 0; p < 4; ++p) {
            float v0 = tile[il * 65 + seg * 8 + p * 2];
            float v1 = tile[il * 65 + seg * 8 + p * 2 + 1];
            __hip_bfloat16 h0 = __float2bfloat16(v0);
            __hip_bfloat16 h1 = __float2bfloat16(v1);
            unsigned short u0 = *reinterpret_cast<unsigned short*>(&h0);
            unsigned short u1 = *reinterpret_cast<unsigned short*>(&h1);
            pk[p] = (unsigned int)u0 | ((unsigned int)u1 << 16);
        }
        uint4 val = make_uint4(pk[0], pk[1], pk[2], pk[3]);
        *(uint4*)&dst[(size_t)(i0 + il) * NC + c0 + seg * 8] = val;
    }
}

__device__ __forceinline__ void rmax_epilogue(float (&rmax)[16], float* gmaxp,
                                              int i0, int wr, int wc, int lr, int lg) {
    #pragma unroll
    for (int u = 0; u < 16; ++u) {
        float v = rmax[u];
        v = fmaxf(v, __shfl_xor(v, 1));
        v = fmaxf(v, __shfl_xor(v, 2));
        v = fmaxf(v, __shfl_xor(v, 4));
        v = fmaxf(v, __shfl_xor(v, 8));
        if (lr == 0) {
            int row = i0 + wr * 64 + (u >> 2) * 16 + lg * 4 + (u & 3);
            gmaxp[(size_t)row * NSLOT + blockIdx.y * 2 + wc] = v;
        }
    }
}

// R7-proven MFMA GEMM driver: 64x64 wave tile, 32 KB LDS, async staging via
// global_load_lds w/ swizzle folded into the global source address.
template <typename F>
__device__ __forceinline__ void gemm_driver(const unsigned short* __restrict__ Xb,
                                            const unsigned short* __restrict__ Yb,
                                            F&& consume) {
    __shared__ char sA[TI * BK * 2];
    __shared__ char sB[TI * BK * 2];
    const int t = threadIdx.x;
    const int w = t >> 6, l = t & 63;
    const int wr = w >> 1, wc = w & 1;
    const int lr = l & 15, lg = l >> 4;
    const int i0 = blockIdx.x * TI;
    const int jbase = blockIdx.y * JCH;

    int aoff[4][2], boff[4][2];
    #pragma unroll
    for (int mt = 0; mt < 4; ++mt) {
        int row = wr * 64 + mt * 16 + lr;
        #pragma unroll
        for (int ks = 0; ks < 2; ++ks) {
            int seg = ks * 4 + lg;
            aoff[mt][ks] = row * 128 + ((seg ^ (row & 7)) * 16);
        }
    }
    #pragma unroll
    for (int nt = 0; nt < 4; ++nt) {
        int row = wc * 64 + nt * 16 + lr;
        #pragma unroll
        for (int ks = 0; ks < 2; ++ks) {
            int seg = ks * 4 + lg;
            boff[nt][ks] = row * 128 + ((seg ^ (row & 7)) * 16);
        }
    }
    const int strow = l >> 3;
    const int stcol = ((l & 7) ^ strow) * 8;
    char* dA0 = sA + (w * 4 + 0) * 1024;
    char* dA1 = sA + (w * 4 + 1) * 1024;
    char* dA2 = sA + (w * 4 + 2) * 1024;
    char* dA3 = sA + (w * 4 + 3) * 1024;
    char* dB0 = sB + (w * 4 + 0) * 1024;
    char* dB1 = sB + (w * 4 + 1) * 1024;
    char* dB2 = sB + (w * 4 + 2) * 1024;
    char* dB3 = sB + (w * 4 + 3) * 1024;
    const unsigned short* ga = Xb + (size_t)(i0 + w * 32 + strow) * NC + stcol;
    const unsigned short* gb0 = Yb + (size_t)(jbase + w * 32 + strow) * NC + stcol;

    #pragma unroll 1
    for (int jt = 0; jt < JCH; jt += TI) {
        const unsigned short* gb = gb0 + (size_t)jt * NC;
        v4f acc[4][4];
        #pragma unroll
        for (int mt = 0; mt < 4; ++mt)
            #pragma unroll
            for (int nt = 0; nt < 4; ++nt)
                acc[mt][nt] = (v4f){0.f, 0.f, 0.f, 0.f};

        #pragma unroll 1
        for (int kt = 0; kt < NC; kt += BK) {
            __syncthreads();
            gload16(ga + kt,           dA0);
            gload16(ga + 8  * NC + kt, dA1);
            gload16(ga + 16 * NC + kt, dA2);
            gload16(ga + 24 * NC + kt, dA3);
            gload16(gb + kt,           dB0);
            gload16(gb + 8  * NC + kt, dB1);
            gload16(gb + 16 * NC + kt, dB2);
            gload16(gb + 24 * NC + kt, dB3);
            __syncthreads();
            #pragma unroll
            for (int ks = 0; ks < 2; ++ks) {
                short8 af[4], bf[4];
                #pragma unroll
                for (int mt = 0; mt < 4; ++mt) af[mt] = *(const short8*)&sA[aoff[mt][ks]];
                #pragma unroll
                for (int nt = 0; nt < 4; ++nt) bf[nt] = *(const short8*)&sB[boff[nt][ks]];
                #pragma unroll
                for (int mt = 0; mt < 4; ++mt)
                    #pragma unroll
                    for (int nt = 0; nt < 4; ++nt)
                        acc[mt][nt] = __builtin_amdgcn_mfma_f32_16x16x32_bf16(
                            af[mt], bf[nt], acc[mt][nt], 0, 0, 0);
            }
        }
        consume(acc, jt);
    }
}

// pass1 (stream): R7 GEMM (inputs pre-normalized -> acc IS the cosine),
// epilogue: row-max partials + fp8-e4m3 packed G store + guarded diag store.
__global__ __launch_bounds__(256, 2) void k_pass1s(const unsigned short* __restrict__ Xb,
                                                   const unsigned short* __restrict__ Yb,
                                                   float* __restrict__ gmaxp,
                                                   float* __restrict__ gdiag,
                                                   unsigned int* __restrict__ G1) {
    const int t = threadIdx.x;
    const int w = t >> 6, l = t & 63;
    const int wr = w >> 1, wc = w & 1;
    const int lr = l & 15, lg = l >> 4;
    const int i0 = blockIdx.x * TI;
    const int jbase = blockIdx.y * JCH;
    float rmax[16];
    #pragma unroll
    for (int u = 0; u < 16; ++u) rmax[u] = -3.0e38f;

    gemm_driver(Xb, Yb, [&](v4f (&acc)[4][4], int jt) {
        const bool diagblk = (jbase + jt == i0);
        #pragma unroll
        for (int mt = 0; mt < 4; ++mt) {
            size_t rbase = (size_t)(i0 / 16 + wr * 4 + mt) * (NT16 * 64);
            #pragma unroll
            for (int nt = 0; nt < 4; ++nt) {
                int ct = (jbase + jt) / 16 + wc * 4 + nt;
                float g0 = acc[mt][nt][0];
                float g1 = acc[mt][nt][1];
                float g2 = acc[mt][nt][2];
                float g3 = acc[mt][nt][3];
                rmax[mt * 4 + 0] = fmaxf(rmax[mt * 4 + 0], g0);
                rmax[mt * 4 + 1] = fmaxf(rmax[mt * 4 + 1], g1);
                rmax[mt * 4 + 2] = fmaxf(rmax[mt * 4 + 2], g2);
                rmax[mt * 4 + 3] = fmaxf(rmax[mt * 4 + 3], g3);
                unsigned int pk = __builtin_amdgcn_cvt_pk_fp8_f32(g0, g1, 0, false);
                pk = __builtin_amdgcn_cvt_pk_fp8_f32(g2, g3, pk, true);
                G1[rbase + (size_t)ct * 64 + l] = pk;
                if (diagblk) {
                    int rowb = i0 + wr * 64 + mt * 16 + lg * 4;
                    int col = jbase + jt + wc * 64 + nt * 16 + lr;
                    if (col == rowb + 0) gdiag[col] = g0;
                    if (col == rowb + 1) gdiag[col] = g1;
                    if (col == rowb + 2) gdiag[col] = g2;
                    if (col == rowb + 3) gdiag[col] = g3;
                }
            }
        }
    });
    rmax_epilogue(rmax, gmaxp, i0, wr, wc, lr, lg);
}

// streaming pass2: read fp8 G tiles, inline dmin, exp-sum Z.
__global__ __launch_bounds__(256) void k_pass2s(const unsigned int* __restrict__ G1,
                                                const float* __restrict__ gmaxp,
                                                float* __restrict__ zp) {
    const int t = threadIdx.x;
    const int w = t >> 6, l = t & 63;
    const int lr = l & 15, lg = l >> 4;
    const int rt = blockIdx.x * 4 + w;
    const int cy = blockIdx.y;

    float m = -3.0e38f;
    {
        int row = rt * 16 + lr;
        #pragma unroll
        for (int k = 0; k < 13; ++k) {
            int s = lg + 4 * k;
            if (s < NSLOT) m = fmaxf(m, gmaxp[(size_t)row * NSLOT + s]);
        }
        m = fmaxf(m, __shfl_xor(m, 16));
        m = fmaxf(m, __shfl_xor(m, 32));
    }
    float inv_lr = 1.0f / ((1.0f - m) + 1e-5f);
    float c1[4], c2[4];
    #pragma unroll
    for (int r = 0; r < 4; ++r) {
        float iv = __shfl(inv_lr, lg * 4 + r);
        c2[r] = 2.0f * iv;
        c1[r] = 2.0f - 2.0f * iv;
    }

    const unsigned int* base = G1 + (size_t)rt * (NT16 * 64) + l;
    float zs[4] = {0.f, 0.f, 0.f, 0.f};
    #pragma unroll 4
    for (int ct = cy * 50; ct < cy * 50 + 50; ++ct) {
        unsigned int v = base[(size_t)ct * 64];
        float g0 = __builtin_amdgcn_cvt_f32_fp8(v, 0);
        float g1 = __builtin_amdgcn_cvt_f32_fp8(v, 1);
        float g2 = __builtin_amdgcn_cvt_f32_fp8(v, 2);
        float g3 = __builtin_amdgcn_cvt_f32_fp8(v, 3);
        zs[0] += __expf(fmaf(c2[0], g0, c1[0]));
        zs[1] += __expf(fmaf(c2[1], g1, c1[1]));
        zs[2] += __expf(fmaf(c2[2], g2, c1[2]));
        zs[3] += __expf(fmaf(c2[3], g3, c1[3]));
    }
    #pragma unroll
    for (int r = 0; r < 4; ++r) {
        float z = zs[r];
        z += __shfl_xor(z, 1);
        z += __shfl_xor(z, 2);
        z += __shfl_xor(z, 4);
        z += __shfl_xor(z, 8);
        if (lr == 0) {
            int row = rt * 16 + lg * 4 + r;
            zp[(size_t)row * NCYS + cy] = z;
        }
    }
}

__global__ void k_kmax_s(const float* __restrict__ zp, const float* __restrict__ gdiag,
                         const float* __restrict__ gmaxp, float* __restrict__ accum,
                         int* __restrict__ counter, float* __restrict__ out) {
    int i = blockIdx.x * 256 + threadIdx.x;
    float Z = 0.f, gmax = -3.0e38f;
    #pragma unroll
    for (int s = 0; s < NCYS; ++s) Z += zp[(size_t)i * NCYS + s];
    #pragma unroll
    for (int s = 0; s < NSLOT; ++s) gmax = fmaxf(gmax, gmaxp[(size_t)i * NSLOT + s]);
    float dmin = 1.0f - gmax;
    float inv = 1.0f / (dmin + 1e-5f);
    float wmx = __expf(2.0f - 2.0f * dmin * inv);
    float wii = __expf(2.0f - 2.0f * (1.0f - gdiag[i]) * inv);
    float invZ = 1.0f / Z;
    float kmax = fmaxf(0.9f * wmx * invZ, 0.9f * wii * invZ + 0.1f);

    __shared__ float red[256];
    red[threadIdx.x] = kmax;
    __syncthreads();
    for (int off = 128; off > 0; off >>= 1) {
        if (threadIdx.x < off) red[threadIdx.x] += red[threadIdx.x + off];
        __syncthreads();
    }
    if (threadIdx.x == 0) {
        atomicAdd(accum, red[0]);
        __threadfence();
        int n = atomicAdd(counter, 1);
        if (n == (int)gridDim.x - 1) {
            float total = atomicAdd(accum, 0.0f);
            out[0] = -logf(total * (1.0f / HW) + 1e-5f);
        }
    }
}

// ---------- fallback path (ws too small for G): two-GEMM, inputs normalized ----------
__global__ __launch_bounds__(256, 2) void k_pass1(const unsigned short* __restrict__ Xb,
                                                  const unsigned short* __restrict__ Yb,
                                                  float* __restrict__ gmaxp) {
    const int t = threadIdx.x;
    const int w = t >> 6, l = t & 63;
    const int wr = w >> 1, wc = w & 1;
    const int lr = l & 15, lg = l >> 4;
    const int i0 = blockIdx.x * TI;
    float rmax[16];
    #pragma unroll
    for (int u = 0; u < 16; ++u) rmax[u] = -3.0e38f;
    gemm_driver(Xb, Yb, [&](v4f (&acc)[4][4], int jt) {
        (void)jt;
        #pragma unroll
        for (int mt = 0; mt < 4; ++mt)
            #pragma unroll
            for (int r = 0; r < 4; ++r) {
                float mm = acc[mt][0][r];
                #pragma unroll
                for (int nt = 1; nt < 4; ++nt) mm = fmaxf(mm, acc[mt][nt][r]);
                rmax[mt * 4 + r] = fmaxf(rmax[mt * 4 + r], mm);
            }
    });
    rmax_epilogue(rmax, gmaxp, i0, wr, wc, lr, lg);
}

__global__ void k_invd(const float* __restrict__ gmaxp, float* __restrict__ invd) {
    int i = blockIdx.x * 256 + threadIdx.x;
    float m = -3.0e38f;
    #pragma unroll
    for (int s = 0; s < NSLOT; ++s) m = fmaxf(m, gmaxp[(size_t)i * NSLOT + s]);
    invd[i] = 1.0f / ((1.0f - m) + 1e-5f);
}

__global__ __launch_bounds__(256, 2) void k_pass2(const unsigned short* __restrict__ Xb,
                                                  const unsigned short* __restrict__ Yb,
                                                  const float* __restrict__ invd,
                                                  float* __restrict__ zp) {
    const int t = threadIdx.x;
    const int w = t >> 6, l = t & 63;
    const int wr = w >> 1, wc = w & 1;
    const int lr = l & 15, lg = l >> 4;
    const int i0 = blockIdx.x * TI;
    float zs[16], c1[16], c2[16];
    #pragma unroll
    for (int u = 0; u < 16; ++u) {
        int row = i0 + wr * 64 + (u >> 2) * 16 + lg * 4 + (u & 3);
        float inv = invd[row];
        c2[u] = 2.0f * inv;
        c1[u] = 2.0f - 2.0f * inv;
        zs[u] = 0.f;
    }
    gemm_driver(Xb, Yb, [&](v4f (&acc)[4][4], int jt) {
        (void)jt;
        #pragma unroll
        for (int mt = 0; mt < 4; ++mt)
            #pragma unroll
            for (int r = 0; r < 4; ++r) {
                int u = mt * 4 + r;
                float s = 0.f;
                #pragma unroll
                for (int nt = 0; nt < 4; ++nt)
                    s += __expf(fmaf(c2[u], acc[mt][nt][r], c1[u]));
                zs[u] += s;
            }
    });
    #pragma unroll
    for (int u = 0; u < 16; ++u) {
        float z = zs[u];
        z += __shfl_xor(z, 1);
        z += __shfl_xor(z, 2);
        z += __shfl_xor(z, 4);
        z += __shfl_xor(z, 8);
        if (lr == 0) {
            int row = i0 + wr * 64 + (u >> 2) * 16 + lg * 4 + (u & 3);
            zp[(size_t)row * NSLOT + blockIdx.y * 2 + wc] = z;
        }
    }
}

__global__ void k_kmax(const float* __restrict__ zp, const float* __restrict__ gmaxp,
                       const unsigned short* __restrict__ Xb, const unsigned short* __restrict__ Yb,
                       float* __restrict__ accum, int* __restrict__ counter,
                       float* __restrict__ out) {
    int i = blockIdx.x * 256 + threadIdx.x;
    float Z = 0.f, gmax = -3.0e38f;
    #pragma unroll
    for (int s = 0; s < NSLOT; ++s) {
        Z += zp[(size_t)i * NSLOT + s];
        gmax = fmaxf(gmax, gmaxp[(size_t)i * NSLOT + s]);
    }
    float gii = 0.f;
    const uint2* xr = (const uint2*)(Xb + (size_t)i * NC);
    const uint2* yr = (const uint2*)(Yb + (size_t)i * NC);
    for (int c4 = 0; c4 < NC / 4; ++c4) {
        uint2 xa = xr[c4], ya = yr[c4];
        float x0 = __uint_as_float((xa.x & 0xFFFFu) << 16), y0 = __uint_as_float((ya.x & 0xFFFFu) << 16);
        float x1 = __uint_as_float(xa.x & 0xFFFF0000u),     y1 = __uint_as_float(ya.x & 0xFFFF0000u);
        float x2 = __uint_as_float((xa.y & 0xFFFFu) << 16), y2 = __uint_as_float((ya.y & 0xFFFFu) << 16);
        float x3 = __uint_as_float(xa.y & 0xFFFF0000u),     y3 = __uint_as_float(ya.y & 0xFFFF0000u);
        gii = fmaf(x0, y0, gii); gii = fmaf(x1, y1, gii);
        gii = fmaf(x2, y2, gii); gii = fmaf(x3, y3, gii);
    }
    float dmin = 1.0f - gmax;
    float inv = 1.0f / (dmin + 1e-5f);
    float wmx = __expf(2.0f - 2.0f * dmin * inv);
    float wii = __expf(2.0f - 2.0f * (1.0f - gii) * inv);
    float invZ = 1.0f / Z;
    float kmax = fmaxf(0.9f * wmx * invZ, 0.9f * wii * invZ + 0.1f);

    __shared__ float red[256];
    red[threadIdx.x] = kmax;
    __syncthreads();
    for (int off = 128; off > 0; off >>= 1) {
        if (threadIdx.x < off) red[threadIdx.x] += red[threadIdx.x + off];
        __syncthreads();
    }
    if (threadIdx.x == 0) {
        atomicAdd(accum, red[0]);
        __threadfence();
        int n = atomicAdd(counter, 1);
        if (n == (int)gridDim.x - 1) {
            float total = atomicAdd(accum, 0.0f);
            out[0] = -logf(total * (1.0f / HW) + 1e-5f);
        }
    }
}

extern "C" void kernel_launch(void* const* d_in, const int* in_sizes, int n_in,
                              void* d_out, int out_size, void* d_ws, size_t ws_size,
                              hipStream_t stream) {
    const float* x = (const float*)d_in[0];
    const float* y = (const float*)d_in[1];
    float* out = (float*)d_out;
    float* ws = (float*)d_ws;

    float* mu    = ws + MU_OFF;
    float* accum = ws + ACC_OFF;
    int*   counter = (int*)(accum + 1);
    float* gmaxp = ws + GMAXP_OFF;
    float* psx   = ws + GMAXP_OFF;            // aliases gmaxp (dead before pass1)
    float* psy   = ws + GMAXP_OFF + 8 * HW;
    float* gdiag = ws + GDIAG_OFF;            // fallback: invd
    float* zp    = ws + ZP_OFF;
    unsigned short* Xb = (unsigned short*)((char*)d_ws + XB_BYTE);
    unsigned short* Yb = (unsigned short*)((char*)d_ws + YB_BYTE);
    unsigned int*   G1 = (unsigned int*)((char*)d_ws + G_BYTE);

    const bool bigws = ws_size >= (G_BYTE + G_BYTES);

    hipMemsetAsync(accum, 0, 64 * sizeof(float), stream);

    hipLaunchKernelGGL(k_mu, dim3(NC), dim3(256), 0, stream, y, mu);
    hipLaunchKernelGGL(k_sumsq, dim3(HW / 256, NC / 64), dim3(256), 0, stream, x, y, mu, psx, psy);
    hipLaunchKernelGGL(k_transpose, dim3(HW / 64, NC / 64, 2), dim3(256), 0, stream,
                       x, y, mu, psx, psy, Xb, Yb);

    dim3 grid(HW / TI, NCH);
    if (bigws) {
        hipLaunchKernelGGL(k_pass1s, grid, dim3(256), 0, stream, Xb, Yb, gmaxp, gdiag, G1);
        hipLaunchKernelGGL(k_pass2s, dim3(NT16 / 4, NCYS), dim3(256), 0, stream, G1, gmaxp, zp);
        hipLaunchKernelGGL(k_kmax_s, dim3(HW / 256), dim3(256), 0, stream, zp, gdiag, gmaxp,
                           accum, counter, out);
    } else {
        hipLaunchKernelGGL(k_pass1, grid, dim3(256), 0, stream, Xb, Yb, gmaxp);
        hipLaunchKernelGGL(k_invd, dim3(HW / 256), dim3(256), 0, stream, gmaxp, gdiag);
        hipLaunchKernelGGL(k_pass2, grid, dim3(256), 0, stream, Xb, Yb, gdiag, zp);
        hipLaunchKernelGGL(k_kmax, dim3(HW / 256), dim3(256), 0, stream, zp, gmaxp, Xb, Yb,
                           accum, counter, out);
    }
}

// Round 12
// 146.159 us; speedup vs baseline: 1.1521x; 1.0689x over previous
//
#include <hip/hip_runtime.h>
#include <hip/hip_bf16.h>
#include <math.h>

#define HW 6400
#define NC 512
#define NH 80
#define NW 80
#define NCH 25      // column chunks (blocks in y) for GEMM passes
#define NSLOT 50    // per-row gmax partial slots = NCH * 2
#define NCYS 4      // column chunks for streaming pass2
#define JCH 256     // columns per GEMM block
#define TI 128      // row tile per GEMM block
#define BK 64       // K tile
#define NT16 400    // 16x16 tiles per dimension (6400/16)
#define NCG 100     // 4-tile column groups (NT16/4)

typedef __attribute__((ext_vector_type(8))) short short8;
typedef __attribute__((ext_vector_type(4))) float v4f;

// ---- workspace layout (float offsets) ----
#define MU_OFF    0
#define ACC_OFF   512                       // accum, counter (zeroed by k_mu)
#define GMAXP_OFF (ACC_OFF + 64)            // HW*NSLOT
#define GDIAG_OFF (GMAXP_OFF + HW*NSLOT)    // HW (fp32 diagonal cos); fallback: invd
#define ZP_OFF    (GDIAG_OFF + HW)          // HW*NSLOT (fallback) / HW*NCYS (stream)
#define F32_FLOATS (ZP_OFF + HW*NSLOT)
#define XB_BYTE   ((size_t)(((F32_FLOATS*4) + 255) & ~255))
#define YB_BYTE   (XB_BYTE + (size_t)HW*NC*2)
#define G_BYTE    (YB_BYTE + (size_t)HW*NC*2)
#define G_BYTES   ((size_t)NT16 * NT16 * 256)   // fp8: 40,960,000

// async global->LDS, 16 B per lane, LDS dest = wave-uniform base + lane*16
typedef __attribute__((address_space(1))) unsigned int uint_g;
typedef __attribute__((address_space(3))) unsigned int uint_l;
__device__ __forceinline__ void gload16(const void* g, void* l) {
    __builtin_amdgcn_global_load_lds((const uint_g*)g, (uint_l*)l, 16, 0, 0);
}

// k_mu also zeroes accum/counter (block 0) — replaces the hipMemsetAsync op.
__global__ void k_mu(const float* __restrict__ y, float* __restrict__ mu,
                     float* __restrict__ acczero) {
    if (blockIdx.x == 0 && threadIdx.x < 64) acczero[threadIdx.x] = 0.f;
    int c = blockIdx.x;
    const float4* yc4 = (const float4*)(y + (size_t)c * HW);
    float s = 0.f;
    for (int i = threadIdx.x; i < HW / 4; i += 256) {
        float4 v = yc4[i];
        s += (v.x + v.y) + (v.z + v.w);
    }
    __shared__ float red[256];
    red[threadIdx.x] = s;
    __syncthreads();
    for (int off = 128; off > 0; off >>= 1) {
        if (threadIdx.x < off) red[threadIdx.x] += red[threadIdx.x + off];
        __syncthreads();
    }
    if (threadIdx.x == 0) mu[c] = red[0] * (1.0f / HW);
}

// fused prep: block = 64 pixels x ALL 512 channels, grid (HW/64, 2).
// phase 1: per-pixel sumsq of (v-mu) (reads 128 KB); phase 2: re-read (L2-hot),
// normalize, transpose, pack bf16 -> dst[i][c].
__global__ void k_prep(const float* __restrict__ x, const float* __restrict__ y,
                       const float* __restrict__ mu,
                       unsigned short* __restrict__ xb, unsigned short* __restrict__ yb) {
    __shared__ float smu[NC];
    __shared__ float part[64][17];
    __shared__ float ssinv[64];
    __shared__ float tile[64 * 65];
    const int t = threadIdx.x;
    const int i0 = blockIdx.x * 64;
    const int z = blockIdx.y;
    const float* src = z ? y : x;
    unsigned short* dst = z ? yb : xb;

    for (int c = t; c < NC; c += 256) smu[c] = mu[c];
    __syncthreads();

    const int p0 = (t & 15) * 4;   // pixel group
    const int g  = t >> 4;         // channel sub-group 0..15
    // phase 1: sumsq partials (thread covers 32 channels for its 4 pixels)
    float a0 = 0.f, a1 = 0.f, a2 = 0.f, a3 = 0.f;
    #pragma unroll 2
    for (int ch = 0; ch < 8; ++ch) {
        #pragma unroll
        for (int it = 0; it < 4; ++it) {
            int cl = ch * 64 + it * 16 + g;
            float m = smu[cl];
            float4 v = *(const float4*)(src + (size_t)cl * HW + i0 + p0);
            float d0 = v.x - m, d1 = v.y - m, d2 = v.z - m, d3 = v.w - m;
            a0 = fmaf(d0, d0, a0); a1 = fmaf(d1, d1, a1);
            a2 = fmaf(d2, d2, a2); a3 = fmaf(d3, d3, a3);
        }
    }
    part[p0 + 0][g] = a0; part[p0 + 1][g] = a1;
    part[p0 + 2][g] = a2; part[p0 + 3][g] = a3;
    __syncthreads();
    if (t < 64) {
        float s = 0.f;
        #pragma unroll
        for (int k = 0; k < 16; ++k) s += part[t][k];
        ssinv[t] = 1.0f / fmaxf(sqrtf(s), 1e-12f);
    }
    __syncthreads();

    // phase 2: normalized transpose, one 64-channel chunk at a time
    for (int ch = 0; ch < 8; ++ch) {
        #pragma unroll
        for (int it = 0; it < 4; ++it) {
            int cl = ch * 64 + it * 16 + g;
            float m = smu[cl];
            float4 v = *(const float4*)(src + (size_t)cl * HW + i0 + p0);
            int clo = it * 16 + g;
            tile[(p0 + 0) * 65 + clo] = (v.x - m) * ssinv[p0 + 0];
            tile[(p0 + 1) * 65 + clo] = (v.y - m) * ssinv[p0 + 1];
            tile[(p0 + 2) * 65 + clo] = (v.z - m) * ssinv[p0 + 2];
            tile[(p0 + 3) * 65 + clo] = (v.w - m) * ssinv[p0 + 3];
        }
        __syncthreads();
        #pragma unroll
        for (int it = 0; it < 2; ++it) {
            int il = t >> 2;
            int seg = (t & 3) + it * 4;
            unsigned int pk[4];
            #pragma unroll
            for (int p = 0; p < 4; ++p) {
                float v0 = tile[il * 65 + seg * 8 + p * 2];
                float v1 = tile[il * 65 + seg * 8 + p * 2 + 1];
                __hip_bfloat16 h0 = __float2bfloat16(v0);
                __hip_bfloat16 h1 = __float2bfloat16(v1);
                unsigned short u0 = *reinterpret_cast<unsigned short*>(&h0);
                unsigned short u1 = *reinterpret_cast<unsigned short*>(&h1);
                pk[p] = (unsigned int)u0 | ((unsigned int)u1 << 16);
            }
            uint4 val = make_uint4(pk[0], pk[1], pk[2], pk[3]);
            *(uint4*)&dst[(size_t)(i0 + il) * NC + ch * 64 + seg * 8] = val;
        }
        __syncthreads();
    }
}

__device__ __forceinline__ void rmax_epilogue(float (&rmax)[16], float* gmaxp,
                                              int i0, int wr, int wc, int lr, int lg) {
    #pragma unroll
    for (int u = 0; u < 16; ++u) {
        float v = rmax[u];
        v = fmaxf(v, __shfl_xor(v, 1));
        v = fmaxf(v, __shfl_xor(v, 2));
        v = fmaxf(v, __shfl_xor(v, 4));
        v = fmaxf(v, __shfl_xor(v, 8));
        if (lr == 0) {
            int row = i0 + wr * 64 + (u >> 2) * 16 + lg * 4 + (u & 3);
            gmaxp[(size_t)row * NSLOT + blockIdx.y * 2 + wc] = v;
        }
    }
}

// R7-proven MFMA GEMM driver: 64x64 wave tile, 32 KB LDS, async staging via
// global_load_lds w/ swizzle folded into the global source address.
template <typename F>
__device__ __forceinline__ void gemm_driver(const unsigned short* __restrict__ Xb,
                                            const unsigned short* __restrict__ Yb,
                                            F&& consume) {
    __shared__ char sA[TI * BK * 2];
    __shared__ char sB[TI * BK * 2];
    const int t = threadIdx.x;
    const int w = t >> 6, l = t & 63;
    const int wr = w >> 1, wc = w & 1;
    const int lr = l & 15, lg = l >> 4;
    const int i0 = blockIdx.x * TI;
    const int jbase = blockIdx.y * JCH;

    int aoff[4][2], boff[4][2];
    #pragma unroll
    for (int mt = 0; mt < 4; ++mt) {
        int row = wr * 64 + mt * 16 + lr;
        #pragma unroll
        for (int ks = 0; ks < 2; ++ks) {
            int seg = ks * 4 + lg;
            aoff[mt][ks] = row * 128 + ((seg ^ (row & 7)) * 16);
        }
    }
    #pragma unroll
    for (int nt = 0; nt < 4; ++nt) {
        int row = wc * 64 + nt * 16 + lr;
        #pragma unroll
        for (int ks = 0; ks < 2; ++ks) {
            int seg = ks * 4 + lg;
            boff[nt][ks] = row * 128 + ((seg ^ (row & 7)) * 16);
        }
    }
    const int strow = l >> 3;
    const int stcol = ((l & 7) ^ strow) * 8;
    char* dA0 = sA + (w * 4 + 0) * 1024;
    char* dA1 = sA + (w * 4 + 1) * 1024;
    char* dA2 = sA + (w * 4 + 2) * 1024;
    char* dA3 = sA + (w * 4 + 3) * 1024;
    char* dB0 = sB + (w * 4 + 0) * 1024;
    char* dB1 = sB + (w * 4 + 1) * 1024;
    char* dB2 = sB + (w * 4 + 2) * 1024;
    char* dB3 = sB + (w * 4 + 3) * 1024;
    const unsigned short* ga = Xb + (size_t)(i0 + w * 32 + strow) * NC + stcol;
    const unsigned short* gb0 = Yb + (size_t)(jbase + w * 32 + strow) * NC + stcol;

    #pragma unroll 1
    for (int jt = 0; jt < JCH; jt += TI) {
        const unsigned short* gb = gb0 + (size_t)jt * NC;
        v4f acc[4][4];
        #pragma unroll
        for (int mt = 0; mt < 4; ++mt)
            #pragma unroll
            for (int nt = 0; nt < 4; ++nt)
                acc[mt][nt] = (v4f){0.f, 0.f, 0.f, 0.f};

        #pragma unroll 1
        for (int kt = 0; kt < NC; kt += BK) {
            __syncthreads();
            gload16(ga + kt,           dA0);
            gload16(ga + 8  * NC + kt, dA1);
            gload16(ga + 16 * NC + kt, dA2);
            gload16(ga + 24 * NC + kt, dA3);
            gload16(gb + kt,           dB0);
            gload16(gb + 8  * NC + kt, dB1);
            gload16(gb + 16 * NC + kt, dB2);
            gload16(gb + 24 * NC + kt, dB3);
            __syncthreads();
            #pragma unroll
            for (int ks = 0; ks < 2; ++ks) {
                short8 af[4], bf[4];
                #pragma unroll
                for (int mt = 0; mt < 4; ++mt) af[mt] = *(const short8*)&sA[aoff[mt][ks]];
                #pragma unroll
                for (int nt = 0; nt < 4; ++nt) bf[nt] = *(const short8*)&sB[boff[nt][ks]];
                #pragma unroll
                for (int mt = 0; mt < 4; ++mt)
                    #pragma unroll
                    for (int nt = 0; nt < 4; ++nt)
                        acc[mt][nt] = __builtin_amdgcn_mfma_f32_16x16x32_bf16(
                            af[mt], bf[nt], acc[mt][nt], 0, 0, 0);
            }
        }
        consume(acc, jt);
    }
}

// pass1 (stream): inputs pre-normalized -> acc IS the cosine. Epilogue:
// row-max partials + fp8 G store as ONE dwordx4 per mt (4 nt tiles packed,
// layout G4[rt][cg][lane]) + diag store guarded to the 50 diag blocks.
__global__ __launch_bounds__(256, 2) void k_pass1s(const unsigned short* __restrict__ Xb,
                                                   const unsigned short* __restrict__ Yb,
                                                   float* __restrict__ gmaxp,
                                                   float* __restrict__ gdiag,
                                                   unsigned int* __restrict__ G1) {
    const int t = threadIdx.x;
    const int w = t >> 6, l = t & 63;
    const int wr = w >> 1, wc = w & 1;
    const int lr = l & 15, lg = l >> 4;
    const int i0 = blockIdx.x * TI;
    const int jbase = blockIdx.y * JCH;
    float rmax[16];
    #pragma unroll
    for (int u = 0; u < 16; ++u) rmax[u] = -3.0e38f;

    gemm_driver(Xb, Yb, [&](v4f (&acc)[4][4], int jt) {
        const bool diagblk = (jbase + jt == i0);
        const int cg = (jbase + jt) / 64 + wc;
        #pragma unroll
        for (int mt = 0; mt < 4; ++mt) {
            unsigned int pks[4];
            #pragma unroll
            for (int nt = 0; nt < 4; ++nt) {
                float g0 = acc[mt][nt][0];
                float g1 = acc[mt][nt][1];
                float g2 = acc[mt][nt][2];
                float g3 = acc[mt][nt][3];
                rmax[mt * 4 + 0] = fmaxf(rmax[mt * 4 + 0], g0);
                rmax[mt * 4 + 1] = fmaxf(rmax[mt * 4 + 1], g1);
                rmax[mt * 4 + 2] = fmaxf(rmax[mt * 4 + 2], g2);
                rmax[mt * 4 + 3] = fmaxf(rmax[mt * 4 + 3], g3);
                unsigned int pk = __builtin_amdgcn_cvt_pk_fp8_f32(g0, g1, 0, false);
                pk = __builtin_amdgcn_cvt_pk_fp8_f32(g2, g3, pk, true);
                pks[nt] = pk;
                if (diagblk) {
                    int rowb = i0 + wr * 64 + mt * 16 + lg * 4;
                    int col = jbase + jt + wc * 64 + nt * 16 + lr;
                    if (col == rowb + 0) gdiag[col] = g0;
                    if (col == rowb + 1) gdiag[col] = g1;
                    if (col == rowb + 2) gdiag[col] = g2;
                    if (col == rowb + 3) gdiag[col] = g3;
                }
            }
            size_t idx = ((size_t)(i0 / 16 + wr * 4 + mt) * NCG + cg) * 64 + l;
            ((uint4*)G1)[idx] = make_uint4(pks[0], pks[1], pks[2], pks[3]);
        }
    });
    rmax_epilogue(rmax, gmaxp, i0, wr, wc, lr, lg);
}

// streaming pass2: uint4 per lane = 4 fp8 tiles (same rows, 4 cols each),
// inline dmin, exp-sum Z. grid (NT16/4, NCYS=4).
__global__ __launch_bounds__(256) void k_pass2s(const unsigned int* __restrict__ G1,
                                                const float* __restrict__ gmaxp,
                                                float* __restrict__ zp) {
    const int t = threadIdx.x;
    const int w = t >> 6, l = t & 63;
    const int lr = l & 15, lg = l >> 4;
    const int rt = blockIdx.x * 4 + w;
    const int cy = blockIdx.y;

    float m = -3.0e38f;
    {
        int row = rt * 16 + lr;
        #pragma unroll
        for (int k = 0; k < 13; ++k) {
            int s = lg + 4 * k;
            if (s < NSLOT) m = fmaxf(m, gmaxp[(size_t)row * NSLOT + s]);
        }
        m = fmaxf(m, __shfl_xor(m, 16));
        m = fmaxf(m, __shfl_xor(m, 32));
    }
    float inv_lr = 1.0f / ((1.0f - m) + 1e-5f);
    float c1[4], c2[4];
    #pragma unroll
    for (int r = 0; r < 4; ++r) {
        float iv = __shfl(inv_lr, lg * 4 + r);
        c2[r] = 2.0f * iv;
        c1[r] = 2.0f - 2.0f * iv;
    }

    const uint4* base = (const uint4*)G1 + (size_t)rt * (NCG * 64) + l;
    float zs[4] = {0.f, 0.f, 0.f, 0.f};
    #pragma unroll 2
    for (int cgk = cy * 25; cgk < cy * 25 + 25; ++cgk) {
        uint4 v = base[(size_t)cgk * 64];
        #pragma unroll
        for (int q = 0; q < 4; ++q) {
            unsigned int pk = (q == 0) ? v.x : (q == 1) ? v.y : (q == 2) ? v.z : v.w;
            float g0 = __builtin_amdgcn_cvt_f32_fp8(pk, 0);
            float g1 = __builtin_amdgcn_cvt_f32_fp8(pk, 1);
            float g2 = __builtin_amdgcn_cvt_f32_fp8(pk, 2);
            float g3 = __builtin_amdgcn_cvt_f32_fp8(pk, 3);
            zs[0] += __expf(fmaf(c2[0], g0, c1[0]));
            zs[1] += __expf(fmaf(c2[1], g1, c1[1]));
            zs[2] += __expf(fmaf(c2[2], g2, c1[2]));
            zs[3] += __expf(fmaf(c2[3], g3, c1[3]));
        }
    }
    #pragma unroll
    for (int r = 0; r < 4; ++r) {
        float z = zs[r];
        z += __shfl_xor(z, 1);
        z += __shfl_xor(z, 2);
        z += __shfl_xor(z, 4);
        z += __shfl_xor(z, 8);
        if (lr == 0) {
            int row = rt * 16 + lg * 4 + r;
            zp[(size_t)row * NCYS + cy] = z;
        }
    }
}

__global__ void k_kmax_s(const float* __restrict__ zp, const float* __restrict__ gdiag,
                         const float* __restrict__ gmaxp, float* __restrict__ accum,
                         int* __restrict__ counter, float* __restrict__ out) {
    int i = blockIdx.x * 256 + threadIdx.x;
    float Z = 0.f, gmax = -3.0e38f;
    #pragma unroll
    for (int s = 0; s < NCYS; ++s) Z += zp[(size_t)i * NCYS + s];
    #pragma unroll
    for (int s = 0; s < NSLOT; ++s) gmax = fmaxf(gmax, gmaxp[(size_t)i * NSLOT + s]);
    float dmin = 1.0f - gmax;
    float inv = 1.0f / (dmin + 1e-5f);
    float wmx = __expf(2.0f - 2.0f * dmin * inv);
    float wii = __expf(2.0f - 2.0f * (1.0f - gdiag[i]) * inv);
    float invZ = 1.0f / Z;
    float kmax = fmaxf(0.9f * wmx * invZ, 0.9f * wii * invZ + 0.1f);

    __shared__ float red[256];
    red[threadIdx.x] = kmax;
    __syncthreads();
    for (int off = 128; off > 0; off >>= 1) {
        if (threadIdx.x < off) red[threadIdx.x] += red[threadIdx.x + off];
        __syncthreads();
    }
    if (threadIdx.x == 0) {
        atomicAdd(accum, red[0]);
        __threadfence();
        int n = atomicAdd(counter, 1);
        if (n == (int)gridDim.x - 1) {
            float total = atomicAdd(accum, 0.0f);
            out[0] = -logf(total * (1.0f / HW) + 1e-5f);
        }
    }
}

// ---------- fallback path (ws too small for G): two-GEMM, inputs normalized ----------
__global__ __launch_bounds__(256, 2) void k_pass1(const unsigned short* __restrict__ Xb,
                                                  const unsigned short* __restrict__ Yb,
                                                  float* __restrict__ gmaxp) {
    const int t = threadIdx.x;
    const int w = t >> 6, l = t & 63;
    const int wr = w >> 1, wc = w & 1;
    const int lr = l & 15, lg = l >> 4;
    const int i0 = blockIdx.x * TI;
    float rmax[16];
    #pragma unroll
    for (int u = 0; u < 16; ++u) rmax[u] = -3.0e38f;
    gemm_driver(Xb, Yb, [&](v4f (&acc)[4][4], int jt) {
        (void)jt;
        #pragma unroll
        for (int mt = 0; mt < 4; ++mt)
            #pragma unroll
            for (int r = 0; r < 4; ++r) {
                float mm = acc[mt][0][r];
                #pragma unroll
                for (int nt = 1; nt < 4; ++nt) mm = fmaxf(mm, acc[mt][nt][r]);
                rmax[mt * 4 + r] = fmaxf(rmax[mt * 4 + r], mm);
            }
    });
    rmax_epilogue(rmax, gmaxp, i0, wr, wc, lr, lg);
}

__global__ void k_invd(const float* __restrict__ gmaxp, float* __restrict__ invd) {
    int i = blockIdx.x * 256 + threadIdx.x;
    float m = -3.0e38f;
    #pragma unroll
    for (int s = 0; s < NSLOT; ++s) m = fmaxf(m, gmaxp[(size_t)i * NSLOT + s]);
    invd[i] = 1.0f / ((1.0f - m) + 1e-5f);
}

__global__ __launch_bounds__(256, 2) void k_pass2(const unsigned short* __restrict__ Xb,
                                                  const unsigned short* __restrict__ Yb,
                                                  const float* __restrict__ invd,
                                                  float* __restrict__ zp) {
    const int t = threadIdx.x;
    const int w = t >> 6, l = t & 63;
    const int wr = w >> 1, wc = w & 1;
    const int lr = l & 15, lg = l >> 4;
    const int i0 = blockIdx.x * TI;
    float zs[16], c1[16], c2[16];
    #pragma unroll
    for (int u = 0; u < 16; ++u) {
        int row = i0 + wr * 64 + (u >> 2) * 16 + lg * 4 + (u & 3);
        float inv = invd[row];
        c2[u] = 2.0f * inv;
        c1[u] = 2.0f - 2.0f * inv;
        zs[u] = 0.f;
    }
    gemm_driver(Xb, Yb, [&](v4f (&acc)[4][4], int jt) {
        (void)jt;
        #pragma unroll
        for (int mt = 0; mt < 4; ++mt)
            #pragma unroll
            for (int r = 0; r < 4; ++r) {
                int u = mt * 4 + r;
                float s = 0.f;
                #pragma unroll
                for (int nt = 0; nt < 4; ++nt)
                    s += __expf(fmaf(c2[u], acc[mt][nt][r], c1[u]));
                zs[u] += s;
            }
    });
    #pragma unroll
    for (int u = 0; u < 16; ++u) {
        float z = zs[u];
        z += __shfl_xor(z, 1);
        z += __shfl_xor(z, 2);
        z += __shfl_xor(z, 4);
        z += __shfl_xor(z, 8);
        if (lr == 0) {
            int row = i0 + wr * 64 + (u >> 2) * 16 + lg * 4 + (u & 3);
            zp[(size_t)row * NSLOT + blockIdx.y * 2 + wc] = z;
        }
    }
}

__global__ void k_kmax(const float* __restrict__ zp, const float* __restrict__ gmaxp,
                       const unsigned short* __restrict__ Xb, const unsigned short* __restrict__ Yb,
                       float* __restrict__ accum, int* __restrict__ counter,
                       float* __restrict__ out) {
    int i = blockIdx.x * 256 + threadIdx.x;
    float Z = 0.f, gmax = -3.0e38f;
    #pragma unroll
    for (int s = 0; s < NSLOT; ++s) {
        Z += zp[(size_t)i * NSLOT + s];
        gmax = fmaxf(gmax, gmaxp[(size_t)i * NSLOT + s]);
    }
    float gii = 0.f;
    const uint2* xr = (const uint2*)(Xb + (size_t)i * NC);
    const uint2* yr = (const uint2*)(Yb + (size_t)i * NC);
    for (int c4 = 0; c4 < NC / 4; ++c4) {
        uint2 xa = xr[c4], ya = yr[c4];
        float x0 = __uint_as_float((xa.x & 0xFFFFu) << 16), y0 = __uint_as_float((ya.x & 0xFFFFu) << 16);
        float x1 = __uint_as_float(xa.x & 0xFFFF0000u),     y1 = __uint_as_float(ya.x & 0xFFFF0000u);
        float x2 = __uint_as_float((xa.y & 0xFFFFu) << 16), y2 = __uint_as_float((ya.y & 0xFFFFu) << 16);
        float x3 = __uint_as_float(xa.y & 0xFFFF0000u),     y3 = __uint_as_float(ya.y & 0xFFFF0000u);
        gii = fmaf(x0, y0, gii); gii = fmaf(x1, y1, gii);
        gii = fmaf(x2, y2, gii); gii = fmaf(x3, y3, gii);
    }
    float dmin = 1.0f - gmax;
    float inv = 1.0f / (dmin + 1e-5f);
    float wmx = __expf(2.0f - 2.0f * dmin * inv);
    float wii = __expf(2.0f - 2.0f * (1.0f - gii) * inv);
    float invZ = 1.0f / Z;
    float kmax = fmaxf(0.9f * wmx * invZ, 0.9f * wii * invZ + 0.1f);

    __shared__ float red[256];
    red[threadIdx.x] = kmax;
    __syncthreads();
    for (int off = 128; off > 0; off >>= 1) {
        if (threadIdx.x < off) red[threadIdx.x] += red[threadIdx.x + off];
        __syncthreads();
    }
    if (threadIdx.x == 0) {
        atomicAdd(accum, red[0]);
        __threadfence();
        int n = atomicAdd(counter, 1);
        if (n == (int)gridDim.x - 1) {
            float total = atomicAdd(accum, 0.0f);
            out[0] = -logf(total * (1.0f / HW) + 1e-5f);
        }
    }
}

extern "C" void kernel_launch(void* const* d_in, const int* in_sizes, int n_in,
                              void* d_out, int out_size, void* d_ws, size_t ws_size,
                              hipStream_t stream) {
    const float* x = (const float*)d_in[0];
    const float* y = (const float*)d_in[1];
    float* out = (float*)d_out;
    float* ws = (float*)d_ws;

    float* mu    = ws + MU_OFF;
    float* accum = ws + ACC_OFF;
    int*   counter = (int*)(accum + 1);
    float* gmaxp = ws + GMAXP_OFF;
    float* gdiag = ws + GDIAG_OFF;            // fallback: invd
    float* zp    = ws + ZP_OFF;
    unsigned short* Xb = (unsigned short*)((char*)d_ws + XB_BYTE);
    unsigned short* Yb = (unsigned short*)((char*)d_ws + YB_BYTE);
    unsigned int*   G1 = (unsigned int*)((char*)d_ws + G_BYTE);

    const bool bigws = ws_size >= (G_BYTE + G_BYTES);

    hipLaunchKernelGGL(k_mu, dim3(NC), dim3(256), 0, stream, y, mu, accum);
    hipLaunchKernelGGL(k_prep, dim3(HW / 64, 2), dim3(256), 0, stream, x, y, mu, Xb, Yb);

    dim3 grid(HW / TI, NCH);
    if (bigws) {
        hipLaunchKernelGGL(k_pass1s, grid, dim3(256), 0, stream, Xb, Yb, gmaxp, gdiag, G1);
        hipLaunchKernelGGL(k_pass2s, dim3(NT16 / 4, NCYS), dim3(256), 0, stream, G1, gmaxp, zp);
        hipLaunchKernelGGL(k_kmax_s, dim3(HW / 256), dim3(256), 0, stream, zp, gdiag, gmaxp,
                           accum, counter, out);
    } else {
        hipLaunchKernelGGL(k_pass1, grid, dim3(256), 0, stream, Xb, Yb, gmaxp);
        hipLaunchKernelGGL(k_invd, dim3(HW / 256), dim3(256), 0, stream, gmaxp, gdiag);
        hipLaunchKernelGGL(k_pass2, grid, dim3(256), 0, stream, Xb, Yb, gdiag, zp);
        hipLaunchKernelGGL(k_kmax, dim3(HW / 256), dim3(256), 0, stream, zp, gmaxp, Xb, Yb,
                           accum, counter, out);
    }
}